// Round 1
// baseline (723.512 us; speedup 1.0000x reference)
//
#include <hip/hip_runtime.h>
#include <stdint.h>

// Problem constants (fixed by the reference)
#define NN 50000
#define EE 800000
#define FF 256
#define HH 256
#define LL 128

typedef __bf16 bf16x8 __attribute__((ext_vector_type(8)));
typedef float  f32x4  __attribute__((ext_vector_type(4)));

typedef __attribute__((address_space(1))) unsigned int uint_as1;
typedef __attribute__((address_space(3))) unsigned int uint_as3;

__device__ __forceinline__ unsigned short f2bf(float f) {
  union { float f; unsigned int u; } v; v.f = f;
  unsigned int u = v.u;
  u += 0x7FFFu + ((u >> 16) & 1u);   // RTNE (finite inputs only)
  return (unsigned short)(u >> 16);
}

__device__ __forceinline__ void gload_lds16(const void* g, void* l) {
  __builtin_amdgcn_global_load_lds((const uint_as1*)g, (uint_as3*)l, 16, 0, 0);
}

// ---------------- casts ----------------
__global__ __launch_bounds__(256) void k_cast_bf16(const float* __restrict__ in,
                                                   unsigned short* __restrict__ out, int n4) {
  int i = blockIdx.x * 256 + threadIdx.x;
  if (i >= n4) return;
  f32x4 x = ((const f32x4*)in)[i];
  ushort4 o;
  o.x = f2bf(x.x); o.y = f2bf(x.y); o.z = f2bf(x.z); o.w = f2bf(x.w);
  ((ushort4*)out)[i] = o;
}

// in: K x Nn (row-major), out: Nn x K (row-major) bf16  (i.e. B^T for the GEMM)
__global__ __launch_bounds__(256) void k_tcast(const float* __restrict__ in,
                                               unsigned short* __restrict__ out, int K, int Nn) {
  int i = blockIdx.x * 256 + threadIdx.x;
  if (i >= K * Nn) return;
  int n = i / K, k = i - n * K;
  out[i] = f2bf(in[k * Nn + n]);
}

// ---------------- CSR build ----------------
__global__ __launch_bounds__(256) void k_hist(const int* __restrict__ rows,
                                              int* __restrict__ cnt, int E) {
  int i = blockIdx.x * 256 + threadIdx.x;
  if (i < E) atomicAdd(&cnt[rows[i]], 1);
}

__global__ __launch_bounds__(1024) void k_scan(const int* __restrict__ cnt,
                                               int* __restrict__ row_start, int n) {
  __shared__ int part[1024];
  int t = threadIdx.x;
  int chunk = (n + 1023) >> 10;
  int lo = t * chunk, hi = min(lo + chunk, n);
  int s = 0;
  for (int i = lo; i < hi; ++i) s += cnt[i];
  part[t] = s;
  __syncthreads();
  for (int off = 1; off < 1024; off <<= 1) {
    int v = (t >= off) ? part[t - off] : 0;
    __syncthreads();
    part[t] += v;
    __syncthreads();
  }
  int run = part[t] - s;  // exclusive
  for (int i = lo; i < hi; ++i) { row_start[i] = run; run += cnt[i]; }
  if (t == 1023) row_start[n] = part[1023];
}

__global__ __launch_bounds__(256) void k_fill(const int* __restrict__ rows,
                                              const int* __restrict__ cols,
                                              const float* __restrict__ vals,
                                              int* __restrict__ cursor,
                                              int* __restrict__ ccol,
                                              float* __restrict__ cval, int E) {
  int i = blockIdx.x * 256 + threadIdx.x;
  if (i < E) {
    int p = atomicAdd(&cursor[rows[i]], 1);
    ccol[p] = cols[i];
    cval[p] = vals[i];
  }
}

// ---------------- SpMM: Y[i] = sum_e val*X[col] + bias ----------------
__global__ __launch_bounds__(256) void k_spmm(const float* __restrict__ X,
                                              const int* __restrict__ row_start,
                                              const int* __restrict__ ccol,
                                              const float* __restrict__ cval,
                                              const float* __restrict__ bias,
                                              float* __restrict__ Y, int n) {
  int row = blockIdx.x * 4 + (threadIdx.x >> 6);
  int lane = threadIdx.x & 63;
  if (row >= n) return;
  int s = row_start[row], e = row_start[row + 1];
  f32x4 a0 = ((const f32x4*)bias)[lane];
  f32x4 a1 = {0.f, 0.f, 0.f, 0.f};
  int p = s;
  for (; p + 1 < e; p += 2) {
    int c0 = ccol[p], c1 = ccol[p + 1];
    float v0 = cval[p], v1 = cval[p + 1];
    f32x4 x0 = ((const f32x4*)(X + (size_t)c0 * HH))[lane];
    f32x4 x1 = ((const f32x4*)(X + (size_t)c1 * HH))[lane];
    a0 += v0 * x0;
    a1 += v1 * x1;
  }
  if (p < e) {
    int c0 = ccol[p];
    float v0 = cval[p];
    a0 += v0 * ((const f32x4*)(X + (size_t)c0 * HH))[lane];
  }
  ((f32x4*)(Y + (size_t)row * HH))[lane] = a0 + a1;
}

// ---------------- BatchNorm ----------------
__global__ __launch_bounds__(256) void k_bnstats(const float* __restrict__ X,
                                                 float* __restrict__ sums, int n) {
  int c = threadIdx.x;
  float s = 0.f, s2 = 0.f;
  for (int r = blockIdx.x; r < n; r += gridDim.x) {
    float v = X[(size_t)r * HH + c];
    s += v; s2 += v * v;
  }
  atomicAdd(&sums[c], s);
  atomicAdd(&sums[HH + c], s2);
}

__global__ __launch_bounds__(256) void k_bnfin(const float* __restrict__ sums,
                                               const float* __restrict__ g,
                                               const float* __restrict__ be,
                                               float* __restrict__ ss, int n) {
  int c = threadIdx.x;
  float inv = 1.f / (float)n;
  float mean = sums[c] * inv;
  float var = sums[HH + c] * inv - mean * mean;
  float sc = g[c] * rsqrtf(var + 1e-5f);
  ss[c] = sc;
  ss[HH + c] = be[c] - mean * sc;
}

// y = bf16(relu(x*scale + shift))
__global__ __launch_bounds__(256) void k_bnrc(const float* __restrict__ X,
                                              const float* __restrict__ ss,
                                              unsigned short* __restrict__ out, int n4) {
  __shared__ float sc[HH], sh[HH];
  int t = threadIdx.x;
  sc[t] = ss[t];
  sh[t] = ss[HH + t];
  __syncthreads();
  int i = blockIdx.x * 256 + t;
  if (i >= n4) return;
  f32x4 x = ((const f32x4*)X)[i];
  int c0 = (i * 4) & (HH - 1);
  ushort4 o;
  o.x = f2bf(fmaxf(x.x * sc[c0 + 0] + sh[c0 + 0], 0.f));
  o.y = f2bf(fmaxf(x.y * sc[c0 + 1] + sh[c0 + 1], 0.f));
  o.z = f2bf(fmaxf(x.z * sc[c0 + 2] + sh[c0 + 2], 0.f));
  o.w = f2bf(fmaxf(x.w * sc[c0 + 3] + sh[c0 + 3], 0.f));
  ((ushort4*)out)[i] = o;
}

// ---------------- GEMM: C(MxNn) = A(MxK,bf16) * Bt(NnxK,bf16)^T + bias ----------------
// 128x128 tile, BK=32, 4 waves (2x2), each wave 4x4 grid of 16x16x32 MFMAs.
// gather != null: A row r is A[gather[r]] (for the final head on idx rows).
__global__ __launch_bounds__(256, 2) void k_gemm(const unsigned short* __restrict__ A,
                                                 const unsigned short* __restrict__ Bt,
                                                 const float* __restrict__ bias,
                                                 float* __restrict__ C,
                                                 int M, int K, int Nn,
                                                 const int* __restrict__ gather) {
  __shared__ unsigned short lA[128 * 32];  // 8 KB, rows of 64B
  __shared__ unsigned short lB[128 * 32];  // 8 KB
  const int tid = threadIdx.x;
  const int wave = tid >> 6, lane = tid & 63;
  const int m0 = blockIdx.x * 128, n0 = blockIdx.y * 128;
  const int wm = (wave >> 1) * 64, wn = (wave & 1) * 64;
  const int lhi = lane >> 4, llo = lane & 15;

  // staging geometry: per issue a wave covers 16 rows x 32 cols (64B rows, 4 lanes/row)
  const int srow = wave * 16 + (lane >> 2);
  const int scol = (lane & 3) * 8;
  int ar0 = m0 + srow, ar1 = m0 + 64 + srow;
  ar0 = ar0 < M ? ar0 : 0;
  ar1 = ar1 < M ? ar1 : 0;
  if (gather) { ar0 = gather[ar0]; ar1 = gather[ar1]; }
  const unsigned short* pA0 = A + (size_t)ar0 * K + scol;
  const unsigned short* pA1 = A + (size_t)ar1 * K + scol;
  const unsigned short* pB0 = Bt + (size_t)(n0 + srow) * K + scol;
  const unsigned short* pB1 = Bt + (size_t)(n0 + 64 + srow) * K + scol;
  unsigned short* dA0 = lA + (wave * 16) * 32;
  unsigned short* dA1 = lA + (64 + wave * 16) * 32;
  unsigned short* dB0 = lB + (wave * 16) * 32;
  unsigned short* dB1 = lB + (64 + wave * 16) * 32;

  f32x4 zero = {0.f, 0.f, 0.f, 0.f};
  f32x4 acc[4][4];
#pragma unroll
  for (int i = 0; i < 4; ++i)
#pragma unroll
    for (int j = 0; j < 4; ++j) acc[i][j] = zero;

  for (int k0 = 0; k0 < K; k0 += 32) {
    gload_lds16(pA0 + k0, dA0);
    gload_lds16(pA1 + k0, dA1);
    gload_lds16(pB0 + k0, dB0);
    gload_lds16(pB1 + k0, dB1);
    __syncthreads();  // drains vmcnt -> LDS valid
    bf16x8 af[4], bfv[4];
#pragma unroll
    for (int mt = 0; mt < 4; ++mt)
      af[mt] = *(const bf16x8*)(lA + (wm + mt * 16 + llo) * 32 + lhi * 8);
#pragma unroll
    for (int nt = 0; nt < 4; ++nt)
      bfv[nt] = *(const bf16x8*)(lB + (wn + nt * 16 + llo) * 32 + lhi * 8);
#pragma unroll
    for (int mt = 0; mt < 4; ++mt)
#pragma unroll
      for (int nt = 0; nt < 4; ++nt)
        acc[mt][nt] = __builtin_amdgcn_mfma_f32_16x16x32_bf16(af[mt], bfv[nt], acc[mt][nt], 0, 0, 0);
    __syncthreads();  // all reads done before next stage
  }

#pragma unroll
  for (int nt = 0; nt < 4; ++nt) {
    int cn = n0 + wn + nt * 16 + llo;
    float bv = bias ? bias[cn] : 0.f;
#pragma unroll
    for (int mt = 0; mt < 4; ++mt) {
      int cm0 = m0 + wm + mt * 16 + lhi * 4;
#pragma unroll
      for (int r = 0; r < 4; ++r) {
        int cm = cm0 + r;
        if (cm < M) C[(size_t)cm * Nn + cn] = acc[mt][nt][r] + bv;
      }
    }
  }
}

extern "C" void kernel_launch(void* const* d_in, const int* in_sizes, int n_in,
                              void* d_out, int out_size, void* d_ws, size_t ws_size,
                              hipStream_t stream) {
  const float* features = (const float*)d_in[0];
  const float* edge_vals = (const float*)d_in[1];
  const float* W1 = (const float*)d_in[2];
  const float* db1 = (const float*)d_in[3];
  const float* b1 = (const float*)d_in[4];
  const float* g1 = (const float*)d_in[5];
  const float* be1 = (const float*)d_in[6];
  const float* W2 = (const float*)d_in[7];
  const float* b2 = (const float*)d_in[8];
  const float* g2 = (const float*)d_in[9];
  const float* be2 = (const float*)d_in[10];
  const float* Wf = (const float*)d_in[11];
  const float* bfb = (const float*)d_in[12];
  const int* erows = (const int*)d_in[13];
  const int* ecols = (const int*)d_in[14];
  const int* idx = (const int*)d_in[15];
  const int M3 = in_sizes[15];
  (void)n_in; (void)out_size; (void)ws_size;

  char* ws = (char*)d_ws;
  size_t off = 0;
  auto alloc = [&](size_t bytes) -> void* {
    void* p = (void*)(ws + off);
    off += (bytes + 255) & ~(size_t)255;
    return p;
  };
  unsigned short* Xb = (unsigned short*)alloc((size_t)NN * HH * 2);  // features bf16 / Hb slot
  float* bigA = (float*)alloc((size_t)NN * HH * 4);                  // gemm out
  float* bigB = (float*)alloc((size_t)NN * HH * 4);                  // spmm out
  unsigned short* W1t = (unsigned short*)alloc((size_t)FF * HH * 2);
  unsigned short* W2t = (unsigned short*)alloc((size_t)HH * HH * 2);
  unsigned short* Wft = (unsigned short*)alloc((size_t)HH * LL * 2);
  int* row_start = (int*)alloc((size_t)(NN + 1) * 4);
  int* cursor = (int*)alloc((size_t)NN * 4);
  int* csr_col = (int*)alloc((size_t)EE * 4);
  float* csr_val = (float*)alloc((size_t)EE * 4);
  float* stats1 = (float*)alloc(4 * HH * 4);  // sum | sumsq | scale | shift
  float* stats2 = (float*)alloc(4 * HH * 4);

  hipMemsetAsync(cursor, 0, (size_t)NN * 4, stream);
  hipMemsetAsync(stats1, 0, 2 * HH * 4, stream);
  hipMemsetAsync(stats2, 0, 2 * HH * 4, stream);

  // casts (weights transposed to NxK bf16 so B-fragments are contiguous)
  k_cast_bf16<<<(NN * FF / 4 + 255) / 256, 256, 0, stream>>>(features, Xb, NN * FF / 4);
  k_tcast<<<(FF * HH + 255) / 256, 256, 0, stream>>>(W1, W1t, FF, HH);
  k_tcast<<<(HH * HH + 255) / 256, 256, 0, stream>>>(W2, W2t, HH, HH);
  k_tcast<<<(HH * LL + 255) / 256, 256, 0, stream>>>(Wf, Wft, HH, LL);

  // CSR build (reused by both SpMMs)
  k_hist<<<(EE + 255) / 256, 256, 0, stream>>>(erows, cursor, EE);
  k_scan<<<1, 1024, 0, stream>>>(cursor, row_start, NN);
  hipMemcpyAsync(cursor, row_start, (size_t)NN * 4, hipMemcpyDeviceToDevice, stream);
  k_fill<<<(EE + 255) / 256, 256, 0, stream>>>(erows, ecols, edge_vals, cursor, csr_col, csr_val, EE);

  // layer 1
  k_gemm<<<dim3((NN + 127) / 128, HH / 128), 256, 0, stream>>>(Xb, W1t, db1, bigA, NN, FF, HH, nullptr);
  k_spmm<<<(NN + 3) / 4, 256, 0, stream>>>(bigA, row_start, csr_col, csr_val, b1, bigB, NN);
  k_bnstats<<<256, 256, 0, stream>>>(bigB, stats1, NN);
  k_bnfin<<<1, HH, 0, stream>>>(stats1, g1, be1, stats1 + 2 * HH, NN);
  k_bnrc<<<(NN * HH / 4 + 255) / 256, 256, 0, stream>>>(bigB, stats1 + 2 * HH, Xb, NN * HH / 4);

  // layer 2
  k_gemm<<<dim3((NN + 127) / 128, HH / 128), 256, 0, stream>>>(Xb, W2t, nullptr, bigA, NN, HH, HH, nullptr);
  k_spmm<<<(NN + 3) / 4, 256, 0, stream>>>(bigA, row_start, csr_col, csr_val, b2, bigB, NN);
  k_bnstats<<<256, 256, 0, stream>>>(bigB, stats2, NN);
  k_bnfin<<<1, HH, 0, stream>>>(stats2, g2, be2, stats2 + 2 * HH, NN);
  k_bnrc<<<(NN * HH / 4 + 255) / 256, 256, 0, stream>>>(bigB, stats2 + 2 * HH, Xb, NN * HH / 4);

  // head: only idx rows, C = Hb[idx] @ Wf + bf
  k_gemm<<<dim3((M3 + 127) / 128, LL / 128), 256, 0, stream>>>(Xb, Wft, bfb, (float*)d_out, M3, HH, LL, idx);
}

// Round 2
// 598.381 us; speedup vs baseline: 1.2091x; 1.2091x over previous
//
#include <hip/hip_runtime.h>
#include <stdint.h>

// Problem constants (fixed by the reference)
#define NN 50000
#define EE 800000
#define FF 256
#define HH 256
#define LL 128

typedef __bf16 bf16x8 __attribute__((ext_vector_type(8)));
typedef float  f32x4  __attribute__((ext_vector_type(4)));

typedef __attribute__((address_space(1))) unsigned int uint_as1;
typedef __attribute__((address_space(3))) unsigned int uint_as3;

__device__ __forceinline__ unsigned short f2bf(float f) {
  union { float f; unsigned int u; } v; v.f = f;
  unsigned int u = v.u;
  u += 0x7FFFu + ((u >> 16) & 1u);   // RTNE (finite inputs only)
  return (unsigned short)(u >> 16);
}

__device__ __forceinline__ float bf2f(unsigned short u) {
  union { unsigned int u; float f; } v;
  v.u = ((unsigned int)u) << 16;
  return v.f;
}

__device__ __forceinline__ f32x4 bf4_to_f32(ushort4 u) {
  f32x4 r;
  r.x = bf2f(u.x); r.y = bf2f(u.y); r.z = bf2f(u.z); r.w = bf2f(u.w);
  return r;
}

__device__ __forceinline__ void gload_lds16(const void* g, void* l) {
  __builtin_amdgcn_global_load_lds((const uint_as1*)g, (uint_as3*)l, 16, 0, 0);
}

// ---------------- casts ----------------
__global__ __launch_bounds__(256) void k_cast_bf16(const float* __restrict__ in,
                                                   unsigned short* __restrict__ out, int n4) {
  int i = blockIdx.x * 256 + threadIdx.x;
  if (i >= n4) return;
  f32x4 x = ((const f32x4*)in)[i];
  ushort4 o;
  o.x = f2bf(x.x); o.y = f2bf(x.y); o.z = f2bf(x.z); o.w = f2bf(x.w);
  ((ushort4*)out)[i] = o;
}

// in: K x Nn (row-major), out: Nn x K (row-major) bf16  (B^T for the GEMM)
__global__ __launch_bounds__(256) void k_tcast(const float* __restrict__ in,
                                               unsigned short* __restrict__ out, int K, int Nn) {
  int i = blockIdx.x * 256 + threadIdx.x;
  if (i >= K * Nn) return;
  int n = i / K, k = i - n * K;
  out[i] = f2bf(in[k * Nn + n]);
}

// ---------------- CSR build ----------------
__global__ __launch_bounds__(256) void k_hist(const int* __restrict__ rows,
                                              int* __restrict__ cnt, int E) {
  int i = blockIdx.x * 256 + threadIdx.x;
  if (i < E) atomicAdd(&cnt[rows[i]], 1);
}

__global__ __launch_bounds__(1024) void k_scan(const int* __restrict__ cnt,
                                               int* __restrict__ row_start, int n) {
  __shared__ int part[1024];
  int t = threadIdx.x;
  int chunk = ((n + 1023) >> 10 | 3) + 1;  // round up to multiple of 4
  int lo = t * chunk;
  int hi = min(lo + chunk, n);
  int s = 0;
  int i = lo;
  for (; i + 3 < hi; i += 4) {
    int4 q = *(const int4*)(cnt + i);
    s += q.x + q.y + q.z + q.w;
  }
  for (; i < hi; ++i) s += cnt[i];
  part[t] = s;
  __syncthreads();
  for (int off = 1; off < 1024; off <<= 1) {
    int v = (t >= off) ? part[t - off] : 0;
    __syncthreads();
    part[t] += v;
    __syncthreads();
  }
  int run = part[t] - s;  // exclusive
  for (i = lo; i < hi; ++i) { row_start[i] = run; run += cnt[i]; }
  if (t == 1023) row_start[n] = part[1023];
}

__global__ __launch_bounds__(256) void k_fill(const int* __restrict__ rows,
                                              const int* __restrict__ cols,
                                              const float* __restrict__ vals,
                                              int* __restrict__ cursor,
                                              int2* __restrict__ csr, int E) {
  int i = blockIdx.x * 256 + threadIdx.x;
  if (i < E) {
    int p = atomicAdd(&cursor[rows[i]], 1);
    int2 pr;
    pr.x = cols[i];
    pr.y = __float_as_int(vals[i]);
    csr[p] = pr;
  }
}

// ---------------- SpMM (bf16 in / bf16 out): Y[i] = sum_e val*X[col] ----------------
// One wave per row; lane handles 4 columns (ushort4 = 8B → 512B/row/wave).
__global__ __launch_bounds__(256) void k_spmm(const unsigned short* __restrict__ X,
                                              const int* __restrict__ row_start,
                                              const int2* __restrict__ csr,
                                              unsigned short* __restrict__ Y, int n) {
  int row = blockIdx.x * 4 + (threadIdx.x >> 6);
  int lane = threadIdx.x & 63;
  if (row >= n) return;
  int s = row_start[row], e = row_start[row + 1];
  f32x4 a0 = {0.f, 0.f, 0.f, 0.f};
  f32x4 a1 = {0.f, 0.f, 0.f, 0.f};
  int p = s;
  for (; p + 1 < e; p += 2) {
    int2 e0 = csr[p], e1 = csr[p + 1];
    ushort4 x0 = ((const ushort4*)(X + (size_t)e0.x * HH))[lane];
    ushort4 x1 = ((const ushort4*)(X + (size_t)e1.x * HH))[lane];
    a0 += __int_as_float(e0.y) * bf4_to_f32(x0);
    a1 += __int_as_float(e1.y) * bf4_to_f32(x1);
  }
  if (p < e) {
    int2 e0 = csr[p];
    ushort4 x0 = ((const ushort4*)(X + (size_t)e0.x * HH))[lane];
    a0 += __int_as_float(e0.y) * bf4_to_f32(x0);
  }
  f32x4 a = a0 + a1;
  ushort4 o;
  o.x = f2bf(a.x); o.y = f2bf(a.y); o.z = f2bf(a.z); o.w = f2bf(a.w);
  ((ushort4*)(Y + (size_t)row * HH))[lane] = o;
}

// ---------------- BatchNorm ----------------
__global__ __launch_bounds__(256) void k_bnstats(const unsigned short* __restrict__ X,
                                                 float* __restrict__ sums, int n) {
  int c = threadIdx.x;
  float s = 0.f, s2 = 0.f;
  for (int r = blockIdx.x; r < n; r += gridDim.x) {
    float v = bf2f(X[(size_t)r * HH + c]);
    s += v; s2 += v * v;
  }
  atomicAdd(&sums[c], s);
  atomicAdd(&sums[HH + c], s2);
}

__global__ __launch_bounds__(256) void k_bnfin(const float* __restrict__ sums,
                                               const float* __restrict__ g,
                                               const float* __restrict__ be,
                                               float* __restrict__ ss, int n) {
  int c = threadIdx.x;
  float inv = 1.f / (float)n;
  float mean = sums[c] * inv;
  float var = sums[HH + c] * inv - mean * mean;
  float sc = g[c] * rsqrtf(var + 1e-5f);
  ss[c] = sc;
  ss[HH + c] = be[c] - mean * sc;
}

// y = bf16(relu(x*scale + shift)), bf16 in
__global__ __launch_bounds__(256) void k_bnrc(const unsigned short* __restrict__ X,
                                              const float* __restrict__ ss,
                                              unsigned short* __restrict__ out, int n4) {
  __shared__ float sc[HH], sh[HH];
  int t = threadIdx.x;
  sc[t] = ss[t];
  sh[t] = ss[HH + t];
  __syncthreads();
  int i = blockIdx.x * 256 + t;
  if (i >= n4) return;
  f32x4 x = bf4_to_f32(((const ushort4*)X)[i]);
  int c0 = (i * 4) & (HH - 1);
  ushort4 o;
  o.x = f2bf(fmaxf(x.x * sc[c0 + 0] + sh[c0 + 0], 0.f));
  o.y = f2bf(fmaxf(x.y * sc[c0 + 1] + sh[c0 + 1], 0.f));
  o.z = f2bf(fmaxf(x.z * sc[c0 + 2] + sh[c0 + 2], 0.f));
  o.w = f2bf(fmaxf(x.w * sc[c0 + 3] + sh[c0 + 3], 0.f));
  ((ushort4*)out)[i] = o;
}

// ---------------- GEMM: C(MxNn) = A(MxK,bf16) * Bt(NnxK,bf16)^T + bias ----------------
// 128x128 tile, BK=32, 4 waves (2x2), each wave 4x4 grid of 16x16x32 MFMAs.
// OUTB=1: write bf16; OUTB=0: write fp32. gather: A row remap (head on idx rows).
template <int OUTB>
__global__ __launch_bounds__(256, 2) void k_gemm(const unsigned short* __restrict__ A,
                                                 const unsigned short* __restrict__ Bt,
                                                 const float* __restrict__ bias,
                                                 void* __restrict__ Cv,
                                                 int M, int K, int Nn,
                                                 const int* __restrict__ gather) {
  __shared__ unsigned short lA[128 * 32];  // 8 KB, rows of 64B
  __shared__ unsigned short lB[128 * 32];  // 8 KB
  const int tid = threadIdx.x;
  const int wave = tid >> 6, lane = tid & 63;
  const int m0 = blockIdx.x * 128, n0 = blockIdx.y * 128;
  const int wm = (wave >> 1) * 64, wn = (wave & 1) * 64;
  const int lhi = lane >> 4, llo = lane & 15;

  // staging geometry: per issue a wave covers 16 rows x 32 cols (64B rows, 4 lanes/row)
  const int srow = wave * 16 + (lane >> 2);
  const int scol = (lane & 3) * 8;
  int ar0 = m0 + srow, ar1 = m0 + 64 + srow;
  ar0 = ar0 < M ? ar0 : 0;
  ar1 = ar1 < M ? ar1 : 0;
  if (gather) { ar0 = gather[ar0]; ar1 = gather[ar1]; }
  const unsigned short* pA0 = A + (size_t)ar0 * K + scol;
  const unsigned short* pA1 = A + (size_t)ar1 * K + scol;
  const unsigned short* pB0 = Bt + (size_t)(n0 + srow) * K + scol;
  const unsigned short* pB1 = Bt + (size_t)(n0 + 64 + srow) * K + scol;
  unsigned short* dA0 = lA + (wave * 16) * 32;
  unsigned short* dA1 = lA + (64 + wave * 16) * 32;
  unsigned short* dB0 = lB + (wave * 16) * 32;
  unsigned short* dB1 = lB + (64 + wave * 16) * 32;

  f32x4 zero = {0.f, 0.f, 0.f, 0.f};
  f32x4 acc[4][4];
#pragma unroll
  for (int i = 0; i < 4; ++i)
#pragma unroll
    for (int j = 0; j < 4; ++j) acc[i][j] = zero;

  for (int k0 = 0; k0 < K; k0 += 32) {
    gload_lds16(pA0 + k0, dA0);
    gload_lds16(pA1 + k0, dA1);
    gload_lds16(pB0 + k0, dB0);
    gload_lds16(pB1 + k0, dB1);
    __syncthreads();  // drains vmcnt -> LDS valid
    bf16x8 af[4], bfv[4];
#pragma unroll
    for (int mt = 0; mt < 4; ++mt)
      af[mt] = *(const bf16x8*)(lA + (wm + mt * 16 + llo) * 32 + lhi * 8);
#pragma unroll
    for (int nt = 0; nt < 4; ++nt)
      bfv[nt] = *(const bf16x8*)(lB + (wn + nt * 16 + llo) * 32 + lhi * 8);
#pragma unroll
    for (int mt = 0; mt < 4; ++mt)
#pragma unroll
      for (int nt = 0; nt < 4; ++nt)
        acc[mt][nt] = __builtin_amdgcn_mfma_f32_16x16x32_bf16(af[mt], bfv[nt], acc[mt][nt], 0, 0, 0);
    __syncthreads();  // all reads done before next stage
  }

#pragma unroll
  for (int nt = 0; nt < 4; ++nt) {
    int cn = n0 + wn + nt * 16 + llo;
    float bv = bias ? bias[cn] : 0.f;
#pragma unroll
    for (int mt = 0; mt < 4; ++mt) {
      int cm0 = m0 + wm + mt * 16 + lhi * 4;
#pragma unroll
      for (int r = 0; r < 4; ++r) {
        int cm = cm0 + r;
        if (cm < M) {
          float v = acc[mt][nt][r] + bv;
          if (OUTB)
            ((unsigned short*)Cv)[(size_t)cm * Nn + cn] = f2bf(v);
          else
            ((float*)Cv)[(size_t)cm * Nn + cn] = v;
        }
      }
    }
  }
}

extern "C" void kernel_launch(void* const* d_in, const int* in_sizes, int n_in,
                              void* d_out, int out_size, void* d_ws, size_t ws_size,
                              hipStream_t stream) {
  const float* features = (const float*)d_in[0];
  const float* edge_vals = (const float*)d_in[1];
  const float* W1 = (const float*)d_in[2];
  const float* db1 = (const float*)d_in[3];
  // d_in[4] = b1  — annihilated by training-mode BN (constant per column before mean-subtract)
  const float* g1 = (const float*)d_in[5];
  const float* be1 = (const float*)d_in[6];
  const float* W2 = (const float*)d_in[7];
  // d_in[8] = b2  — annihilated by BN
  const float* g2 = (const float*)d_in[9];
  const float* be2 = (const float*)d_in[10];
  const float* Wf = (const float*)d_in[11];
  const float* bfb = (const float*)d_in[12];
  const int* erows = (const int*)d_in[13];
  const int* ecols = (const int*)d_in[14];
  const int* idx = (const int*)d_in[15];
  const int M3 = in_sizes[15];
  (void)n_in; (void)out_size; (void)ws_size;

  char* ws = (char*)d_ws;
  size_t off = 0;
  auto alloc = [&](size_t bytes) -> void* {
    void* p = (void*)(ws + off);
    off += (bytes + 255) & ~(size_t)255;
    return p;
  };
  unsigned short* Xb = (unsigned short*)alloc((size_t)NN * HH * 2);  // features / hidden (bf16)
  unsigned short* Ab = (unsigned short*)alloc((size_t)NN * HH * 2);  // gemm out (bf16)
  unsigned short* Yb = (unsigned short*)alloc((size_t)NN * HH * 2);  // spmm out (bf16)
  unsigned short* W1t = (unsigned short*)alloc((size_t)FF * HH * 2);
  unsigned short* W2t = (unsigned short*)alloc((size_t)HH * HH * 2);
  unsigned short* Wft = (unsigned short*)alloc((size_t)HH * LL * 2);
  int* row_start = (int*)alloc((size_t)(NN + 1) * 4);
  int* cursor = (int*)alloc((size_t)NN * 4);
  int2* csr = (int2*)alloc((size_t)EE * 8);
  float* stats = (float*)alloc(8 * HH * 4);  // sums1|ss1|sums2|ss2
  float* sums1 = stats, *ss1 = stats + 2 * HH;
  float* sums2 = stats + 4 * HH, *ss2 = stats + 6 * HH;

  hipMemsetAsync(cursor, 0, (size_t)NN * 4, stream);
  hipMemsetAsync(stats, 0, 8 * HH * 4, stream);

  // casts (weights transposed to NxK bf16 so B-fragments are contiguous)
  k_cast_bf16<<<(NN * FF / 4 + 255) / 256, 256, 0, stream>>>(features, Xb, NN * FF / 4);
  k_tcast<<<(FF * HH + 255) / 256, 256, 0, stream>>>(W1, W1t, FF, HH);
  k_tcast<<<(HH * HH + 255) / 256, 256, 0, stream>>>(W2, W2t, HH, HH);
  k_tcast<<<(HH * LL + 255) / 256, 256, 0, stream>>>(Wf, Wft, HH, LL);

  // CSR build (reused by both SpMMs)
  k_hist<<<(EE + 255) / 256, 256, 0, stream>>>(erows, cursor, EE);
  k_scan<<<1, 1024, 0, stream>>>(cursor, row_start, NN);
  hipMemcpyAsync(cursor, row_start, (size_t)NN * 4, hipMemcpyDeviceToDevice, stream);
  k_fill<<<(EE + 255) / 256, 256, 0, stream>>>(erows, ecols, edge_vals, cursor, csr, EE);

  // layer 1
  k_gemm<1><<<dim3((NN + 127) / 128, HH / 128), 256, 0, stream>>>(Xb, W1t, db1, Ab, NN, FF, HH, nullptr);
  k_spmm<<<(NN + 3) / 4, 256, 0, stream>>>(Ab, row_start, csr, Yb, NN);
  k_bnstats<<<256, 256, 0, stream>>>(Yb, sums1, NN);
  k_bnfin<<<1, HH, 0, stream>>>(sums1, g1, be1, ss1, NN);
  k_bnrc<<<(NN * HH / 4 + 255) / 256, 256, 0, stream>>>(Yb, ss1, Xb, NN * HH / 4);

  // layer 2
  k_gemm<1><<<dim3((NN + 127) / 128, HH / 128), 256, 0, stream>>>(Xb, W2t, nullptr, Ab, NN, HH, HH, nullptr);
  k_spmm<<<(NN + 3) / 4, 256, 0, stream>>>(Ab, row_start, csr, Yb, NN);
  k_bnstats<<<256, 256, 0, stream>>>(Yb, sums2, NN);
  k_bnfin<<<1, HH, 0, stream>>>(sums2, g2, be2, ss2, NN);
  k_bnrc<<<(NN * HH / 4 + 255) / 256, 256, 0, stream>>>(Yb, ss2, Xb, NN * HH / 4);

  // head: only idx rows, C = H[idx] @ Wf + bf
  k_gemm<0><<<dim3((M3 + 127) / 128, LL / 128), 256, 0, stream>>>(Xb, Wft, bfb, d_out, M3, HH, LL, idx);
}

// Round 3
// 545.954 us; speedup vs baseline: 1.3252x; 1.0960x over previous
//
#include <hip/hip_runtime.h>
#include <stdint.h>

// Problem constants (fixed by the reference)
#define NN 50000
#define EE 800000
#define FF 256
#define HH 256
#define LL 128

typedef __bf16 bf16x8 __attribute__((ext_vector_type(8)));
typedef float  f32x4  __attribute__((ext_vector_type(4)));

typedef __attribute__((address_space(1))) unsigned int uint_as1;
typedef __attribute__((address_space(3))) unsigned int uint_as3;

__device__ __forceinline__ unsigned short f2bf(float f) {
  union { float f; unsigned int u; } v; v.f = f;
  unsigned int u = v.u;
  u += 0x7FFFu + ((u >> 16) & 1u);   // RTNE (finite inputs only)
  return (unsigned short)(u >> 16);
}

__device__ __forceinline__ float bf2f(unsigned short u) {
  union { unsigned int u; float f; } v;
  v.u = ((unsigned int)u) << 16;
  return v.f;
}

__device__ __forceinline__ f32x4 bf4_to_f32(ushort4 u) {
  f32x4 r;
  r.x = bf2f(u.x); r.y = bf2f(u.y); r.z = bf2f(u.z); r.w = bf2f(u.w);
  return r;
}

__device__ __forceinline__ void gload_lds16(const void* g, void* l) {
  __builtin_amdgcn_global_load_lds((const uint_as1*)g, (uint_as3*)l, 16, 0, 0);
}

// ---------------- casts ----------------
__global__ __launch_bounds__(256) void k_cast_bf16(const float* __restrict__ in,
                                                   unsigned short* __restrict__ out, int n4) {
  int i = blockIdx.x * 256 + threadIdx.x;
  if (i >= n4) return;
  f32x4 x = ((const f32x4*)in)[i];
  ushort4 o;
  o.x = f2bf(x.x); o.y = f2bf(x.y); o.z = f2bf(x.z); o.w = f2bf(x.w);
  ((ushort4*)out)[i] = o;
}

// in: K x Nn (row-major), out: Nn x K (row-major) bf16  (B^T for the GEMM)
__global__ __launch_bounds__(256) void k_tcast(const float* __restrict__ in,
                                               unsigned short* __restrict__ out, int K, int Nn) {
  int i = blockIdx.x * 256 + threadIdx.x;
  if (i >= K * Nn) return;
  int n = i / K, k = i - n * K;
  out[i] = f2bf(in[k * Nn + n]);
}

// ---------------- CSR build ----------------
__global__ __launch_bounds__(256) void k_hist(const int* __restrict__ rows,
                                              int* __restrict__ cnt, int E) {
  int i = blockIdx.x * 256 + threadIdx.x;
  if (i < E) atomicAdd(&cnt[rows[i]], 1);
}

// Unordered exclusive allocation: wave-scan of counts + one global atomic per wave.
// Writes row_start (kept for spmm) and cursor (consumed by k_fill).
__global__ __launch_bounds__(256) void k_alloc(const int* __restrict__ cnt,
                                               int* __restrict__ row_start,
                                               int* __restrict__ cursor,
                                               int* __restrict__ total, int n) {
  int i = blockIdx.x * 256 + threadIdx.x;
  int lane = threadIdx.x & 63;
  int c = (i < n) ? cnt[i] : 0;
  int incl = c;
#pragma unroll
  for (int off = 1; off < 64; off <<= 1) {
    int v = __shfl_up(incl, off, 64);
    if (lane >= off) incl += v;
  }
  int excl = incl - c;
  int wtot = __shfl(incl, 63, 64);
  int base = 0;
  if (lane == 0) base = atomicAdd(total, wtot);
  base = __shfl(base, 0, 64);
  if (i < n) {
    int s = base + excl;
    row_start[i] = s;
    cursor[i] = s;
  }
}

__global__ __launch_bounds__(256) void k_fill(const int* __restrict__ rows,
                                              const int* __restrict__ cols,
                                              const float* __restrict__ vals,
                                              int* __restrict__ cursor,
                                              int2* __restrict__ csr, int E) {
  int i = blockIdx.x * 256 + threadIdx.x;
  if (i < E) {
    int p = atomicAdd(&cursor[rows[i]], 1);
    int2 pr;
    pr.x = cols[i];
    pr.y = __float_as_int(vals[i]);
    csr[p] = pr;
  }
}

// ---------------- SpMM (bf16 in / bf16 out): Y[i] = sum_e val*X[col] ----------------
// One wave per row; lane handles 4 columns (ushort4 = 8B -> 512B/row/wave).
__global__ __launch_bounds__(256) void k_spmm(const unsigned short* __restrict__ X,
                                              const int* __restrict__ row_start,
                                              const int* __restrict__ cnt,
                                              const int2* __restrict__ csr,
                                              unsigned short* __restrict__ Y, int n) {
  int row = blockIdx.x * 4 + (threadIdx.x >> 6);
  int lane = threadIdx.x & 63;
  if (row >= n) return;
  int s = row_start[row], e = s + cnt[row];
  f32x4 a0 = {0.f, 0.f, 0.f, 0.f};
  f32x4 a1 = {0.f, 0.f, 0.f, 0.f};
  int p = s;
  for (; p + 1 < e; p += 2) {
    int2 e0 = csr[p], e1 = csr[p + 1];
    ushort4 x0 = ((const ushort4*)(X + (size_t)e0.x * HH))[lane];
    ushort4 x1 = ((const ushort4*)(X + (size_t)e1.x * HH))[lane];
    a0 += __int_as_float(e0.y) * bf4_to_f32(x0);
    a1 += __int_as_float(e1.y) * bf4_to_f32(x1);
  }
  if (p < e) {
    int2 e0 = csr[p];
    ushort4 x0 = ((const ushort4*)(X + (size_t)e0.x * HH))[lane];
    a0 += __int_as_float(e0.y) * bf4_to_f32(x0);
  }
  f32x4 a = a0 + a1;
  ushort4 o;
  o.x = f2bf(a.x); o.y = f2bf(a.y); o.z = f2bf(a.z); o.w = f2bf(a.w);
  ((ushort4*)(Y + (size_t)row * HH))[lane] = o;
}

// ---------------- BatchNorm ----------------
__global__ __launch_bounds__(256) void k_bnstats(const unsigned short* __restrict__ X,
                                                 float* __restrict__ sums, int n) {
  int c = threadIdx.x;
  float s = 0.f, s2 = 0.f;
  for (int r = blockIdx.x; r < n; r += gridDim.x) {
    float v = bf2f(X[(size_t)r * HH + c]);
    s += v; s2 += v * v;
  }
  atomicAdd(&sums[c], s);
  atomicAdd(&sums[HH + c], s2);
}

__global__ __launch_bounds__(256) void k_bnfin(const float* __restrict__ sums,
                                               const float* __restrict__ g,
                                               const float* __restrict__ be,
                                               float* __restrict__ ss, int n) {
  int c = threadIdx.x;
  float inv = 1.f / (float)n;
  float mean = sums[c] * inv;
  float var = sums[HH + c] * inv - mean * mean;
  float sc = g[c] * rsqrtf(var + 1e-5f);
  ss[c] = sc;
  ss[HH + c] = be[c] - mean * sc;
}

// y = bf16(relu(x*scale + shift)), bf16 in
__global__ __launch_bounds__(256) void k_bnrc(const unsigned short* __restrict__ X,
                                              const float* __restrict__ ss,
                                              unsigned short* __restrict__ out, int n4) {
  __shared__ float sc[HH], sh[HH];
  int t = threadIdx.x;
  sc[t] = ss[t];
  sh[t] = ss[HH + t];
  __syncthreads();
  int i = blockIdx.x * 256 + t;
  if (i >= n4) return;
  f32x4 x = bf4_to_f32(((const ushort4*)X)[i]);
  int c0 = (i * 4) & (HH - 1);
  ushort4 o;
  o.x = f2bf(fmaxf(x.x * sc[c0 + 0] + sh[c0 + 0], 0.f));
  o.y = f2bf(fmaxf(x.y * sc[c0 + 1] + sh[c0 + 1], 0.f));
  o.z = f2bf(fmaxf(x.z * sc[c0 + 2] + sh[c0 + 2], 0.f));
  o.w = f2bf(fmaxf(x.w * sc[c0 + 3] + sh[c0 + 3], 0.f));
  ((ushort4*)out)[i] = o;
}

// ---------------- GEMM: C(MxNn) = A(MxK,bf16) * Bt(NnxK,bf16)^T + bias ----------------
// 128x128 tile, BK=32, 4 waves (2x2), each wave 4x4 grid of 16x16x32 MFMAs.
// OUTB=1: write bf16; OUTB=0: write fp32. gather: A row remap (head on idx rows).
template <int OUTB>
__global__ __launch_bounds__(256, 2) void k_gemm(const unsigned short* __restrict__ A,
                                                 const unsigned short* __restrict__ Bt,
                                                 const float* __restrict__ bias,
                                                 void* __restrict__ Cv,
                                                 int M, int K, int Nn,
                                                 const int* __restrict__ gather) {
  __shared__ unsigned short lA[128 * 32];  // 8 KB, rows of 64B
  __shared__ unsigned short lB[128 * 32];  // 8 KB
  const int tid = threadIdx.x;
  const int wave = tid >> 6, lane = tid & 63;
  const int m0 = blockIdx.x * 128, n0 = blockIdx.y * 128;
  const int wm = (wave >> 1) * 64, wn = (wave & 1) * 64;
  const int lhi = lane >> 4, llo = lane & 15;

  // staging geometry: per issue a wave covers 16 rows x 32 cols (64B rows, 4 lanes/row)
  const int srow = wave * 16 + (lane >> 2);
  const int scol = (lane & 3) * 8;
  int ar0 = m0 + srow, ar1 = m0 + 64 + srow;
  ar0 = ar0 < M ? ar0 : 0;
  ar1 = ar1 < M ? ar1 : 0;
  if (gather) { ar0 = gather[ar0]; ar1 = gather[ar1]; }
  const unsigned short* pA0 = A + (size_t)ar0 * K + scol;
  const unsigned short* pA1 = A + (size_t)ar1 * K + scol;
  const unsigned short* pB0 = Bt + (size_t)(n0 + srow) * K + scol;
  const unsigned short* pB1 = Bt + (size_t)(n0 + 64 + srow) * K + scol;
  unsigned short* dA0 = lA + (wave * 16) * 32;
  unsigned short* dA1 = lA + (64 + wave * 16) * 32;
  unsigned short* dB0 = lB + (wave * 16) * 32;
  unsigned short* dB1 = lB + (64 + wave * 16) * 32;

  f32x4 zero = {0.f, 0.f, 0.f, 0.f};
  f32x4 acc[4][4];
#pragma unroll
  for (int i = 0; i < 4; ++i)
#pragma unroll
    for (int j = 0; j < 4; ++j) acc[i][j] = zero;

  for (int k0 = 0; k0 < K; k0 += 32) {
    gload_lds16(pA0 + k0, dA0);
    gload_lds16(pA1 + k0, dA1);
    gload_lds16(pB0 + k0, dB0);
    gload_lds16(pB1 + k0, dB1);
    __syncthreads();  // drains vmcnt -> LDS valid
    bf16x8 af[4], bfv[4];
#pragma unroll
    for (int mt = 0; mt < 4; ++mt)
      af[mt] = *(const bf16x8*)(lA + (wm + mt * 16 + llo) * 32 + lhi * 8);
#pragma unroll
    for (int nt = 0; nt < 4; ++nt)
      bfv[nt] = *(const bf16x8*)(lB + (wn + nt * 16 + llo) * 32 + lhi * 8);
#pragma unroll
    for (int mt = 0; mt < 4; ++mt)
#pragma unroll
      for (int nt = 0; nt < 4; ++nt)
        acc[mt][nt] = __builtin_amdgcn_mfma_f32_16x16x32_bf16(af[mt], bfv[nt], acc[mt][nt], 0, 0, 0);
    __syncthreads();  // all reads done before next stage
  }

#pragma unroll
  for (int nt = 0; nt < 4; ++nt) {
    int cn = n0 + wn + nt * 16 + llo;
    float bv = bias ? bias[cn] : 0.f;
#pragma unroll
    for (int mt = 0; mt < 4; ++mt) {
      int cm0 = m0 + wm + mt * 16 + lhi * 4;
#pragma unroll
      for (int r = 0; r < 4; ++r) {
        int cm = cm0 + r;
        if (cm < M) {
          float v = acc[mt][nt][r] + bv;
          if (OUTB)
            ((unsigned short*)Cv)[(size_t)cm * Nn + cn] = f2bf(v);
          else
            ((float*)Cv)[(size_t)cm * Nn + cn] = v;
        }
      }
    }
  }
}

extern "C" void kernel_launch(void* const* d_in, const int* in_sizes, int n_in,
                              void* d_out, int out_size, void* d_ws, size_t ws_size,
                              hipStream_t stream) {
  const float* features = (const float*)d_in[0];
  const float* edge_vals = (const float*)d_in[1];
  const float* W1 = (const float*)d_in[2];
  const float* db1 = (const float*)d_in[3];
  // d_in[4] = b1  — annihilated by training-mode BN (constant per column before mean-subtract)
  const float* g1 = (const float*)d_in[5];
  const float* be1 = (const float*)d_in[6];
  const float* W2 = (const float*)d_in[7];
  // d_in[8] = b2  — annihilated by BN
  const float* g2 = (const float*)d_in[9];
  const float* be2 = (const float*)d_in[10];
  const float* Wf = (const float*)d_in[11];
  const float* bfb = (const float*)d_in[12];
  const int* erows = (const int*)d_in[13];
  const int* ecols = (const int*)d_in[14];
  const int* idx = (const int*)d_in[15];
  const int M3 = in_sizes[15];
  (void)n_in; (void)out_size; (void)ws_size;

  char* ws = (char*)d_ws;
  size_t off = 0;
  auto alloc = [&](size_t bytes) -> void* {
    void* p = (void*)(ws + off);
    off += (bytes + 255) & ~(size_t)255;
    return p;
  };
  unsigned short* Xb = (unsigned short*)alloc((size_t)NN * HH * 2);  // features / hidden (bf16)
  unsigned short* Ab = (unsigned short*)alloc((size_t)NN * HH * 2);  // gemm out (bf16)
  unsigned short* Yb = (unsigned short*)alloc((size_t)NN * HH * 2);  // spmm out (bf16)
  unsigned short* W1t = (unsigned short*)alloc((size_t)FF * HH * 2);
  unsigned short* W2t = (unsigned short*)alloc((size_t)HH * HH * 2);
  unsigned short* Wft = (unsigned short*)alloc((size_t)HH * LL * 2);
  int* row_start = (int*)alloc((size_t)NN * 4);
  int* cursor = (int*)alloc((size_t)NN * 4);
  int* cnt = (int*)alloc((size_t)NN * 4);
  int2* csr = (int2*)alloc((size_t)EE * 8);
  float* stats = (float*)alloc(8 * HH * 4 + 256);  // sums1|ss1|sums2|ss2|total
  float* sums1 = stats, *ss1 = stats + 2 * HH;
  float* sums2 = stats + 4 * HH, *ss2 = stats + 6 * HH;
  int* total = (int*)(stats + 8 * HH);

  hipMemsetAsync(cnt, 0, (size_t)NN * 4, stream);
  hipMemsetAsync(stats, 0, 8 * HH * 4 + 256, stream);

  // casts (weights transposed to NxK bf16 so B-fragments are contiguous)
  k_cast_bf16<<<(NN * FF / 4 + 255) / 256, 256, 0, stream>>>(features, Xb, NN * FF / 4);
  k_tcast<<<(FF * HH + 255) / 256, 256, 0, stream>>>(W1, W1t, FF, HH);
  k_tcast<<<(HH * HH + 255) / 256, 256, 0, stream>>>(W2, W2t, HH, HH);
  k_tcast<<<(HH * LL + 255) / 256, 256, 0, stream>>>(Wf, Wft, HH, LL);

  // CSR build (reused by both SpMMs); row bases via unordered atomic allocation
  k_hist<<<(EE + 255) / 256, 256, 0, stream>>>(erows, cnt, EE);
  k_alloc<<<(NN + 255) / 256, 256, 0, stream>>>(cnt, row_start, cursor, total, NN);
  k_fill<<<(EE + 255) / 256, 256, 0, stream>>>(erows, ecols, edge_vals, cursor, csr, EE);

  // layer 1
  k_gemm<1><<<dim3((NN + 127) / 128, HH / 128), 256, 0, stream>>>(Xb, W1t, db1, Ab, NN, FF, HH, nullptr);
  k_spmm<<<(NN + 3) / 4, 256, 0, stream>>>(Ab, row_start, cnt, csr, Yb, NN);
  k_bnstats<<<256, 256, 0, stream>>>(Yb, sums1, NN);
  k_bnfin<<<1, HH, 0, stream>>>(sums1, g1, be1, ss1, NN);
  k_bnrc<<<(NN * HH / 4 + 255) / 256, 256, 0, stream>>>(Yb, ss1, Xb, NN * HH / 4);

  // layer 2
  k_gemm<1><<<dim3((NN + 127) / 128, HH / 128), 256, 0, stream>>>(Xb, W2t, nullptr, Ab, NN, HH, HH, nullptr);
  k_spmm<<<(NN + 3) / 4, 256, 0, stream>>>(Ab, row_start, cnt, csr, Yb, NN);
  k_bnstats<<<256, 256, 0, stream>>>(Yb, sums2, NN);
  k_bnfin<<<1, HH, 0, stream>>>(sums2, g2, be2, ss2, NN);
  k_bnrc<<<(NN * HH / 4 + 255) / 256, 256, 0, stream>>>(Yb, ss2, Xb, NN * HH / 4);

  // head: only idx rows, C = H[idx] @ Wf + bf
  k_gemm<0><<<dim3((M3 + 127) / 128, LL / 128), 256, 0, stream>>>(Xb, Wft, bfb, d_out, M3, HH, LL, idx);
}

// Round 4
// 511.476 us; speedup vs baseline: 1.4146x; 1.0674x over previous
//
#include <hip/hip_runtime.h>
#include <stdint.h>

// Problem constants (fixed by the reference)
#define NN 50000
#define EE 800000
#define FF 256
#define HH 256
#define LL 128

typedef __bf16 bf16x8 __attribute__((ext_vector_type(8)));
typedef float  f32x4  __attribute__((ext_vector_type(4)));

typedef __attribute__((address_space(1))) unsigned int uint_as1;
typedef __attribute__((address_space(3))) unsigned int uint_as3;

__device__ __forceinline__ unsigned short f2bf(float f) {
  union { float f; unsigned int u; } v; v.f = f;
  unsigned int u = v.u;
  u += 0x7FFFu + ((u >> 16) & 1u);   // RTNE (finite inputs only)
  return (unsigned short)(u >> 16);
}

__device__ __forceinline__ float bf2f(unsigned short u) {
  union { unsigned int u; float f; } v;
  v.u = ((unsigned int)u) << 16;
  return v.f;
}

__device__ __forceinline__ f32x4 bf4_to_f32(ushort4 u) {
  f32x4 r;
  r.x = bf2f(u.x); r.y = bf2f(u.y); r.z = bf2f(u.z); r.w = bf2f(u.w);
  return r;
}

__device__ __forceinline__ void gload_lds16(const void* g, void* l) {
  __builtin_amdgcn_global_load_lds((const uint_as1*)g, (uint_as3*)l, 16, 0, 0);
}

// ---------------- fused casts: features (vec) + 3 weight transpose-casts ----------------
// grid partition: [0,12500) features, [12500,12756) W1, [12756,13012) W2, [13012,13140) Wf
__global__ __launch_bounds__(256) void k_casts(const float* __restrict__ features,
                                               unsigned short* __restrict__ Xb,
                                               const float* __restrict__ W1,
                                               unsigned short* __restrict__ W1t,
                                               const float* __restrict__ W2,
                                               unsigned short* __restrict__ W2t,
                                               const float* __restrict__ Wf,
                                               unsigned short* __restrict__ Wft) {
  int b = blockIdx.x, t = threadIdx.x;
  if (b < 12500) {
    int i = b * 256 + t;  // n4 = 3,200,000 exactly
    f32x4 x = ((const f32x4*)features)[i];
    ushort4 o;
    o.x = f2bf(x.x); o.y = f2bf(x.y); o.z = f2bf(x.z); o.w = f2bf(x.w);
    ((ushort4*)Xb)[i] = o;
  } else if (b < 13012) {
    // W1 / W2: K=256, Nn=256, 65536 elems = 256 blocks each
    const float* in = (b < 12756) ? W1 : W2;
    unsigned short* out = (b < 12756) ? W1t : W2t;
    int i = ((b < 12756) ? (b - 12500) : (b - 12756)) * 256 + t;
    int n = i >> 8, k = i & 255;
    out[i] = f2bf(in[k * HH + n]);
  } else {
    // Wf: K=256 (HH), Nn=128 (LL), 32768 elems = 128 blocks
    int i = (b - 13012) * 256 + t;
    int n = i >> 8, k = i & 255;  // out is LL x HH (n in [0,128))
    Wft[i] = f2bf(Wf[k * LL + n]);
  }
}

// ---------------- CSR build ----------------
__global__ __launch_bounds__(256) void k_hist(const int* __restrict__ rows,
                                              int* __restrict__ cnt, int E) {
  int i = blockIdx.x * 256 + threadIdx.x;
  if (i < E) atomicAdd(&cnt[rows[i]], 1);
}

// Unordered exclusive allocation: wave-scan of counts + one global atomic per wave.
__global__ __launch_bounds__(256) void k_alloc(const int* __restrict__ cnt,
                                               int* __restrict__ cursor,
                                               int* __restrict__ total, int n) {
  int i = blockIdx.x * 256 + threadIdx.x;
  int lane = threadIdx.x & 63;
  int c = (i < n) ? cnt[i] : 0;
  int incl = c;
#pragma unroll
  for (int off = 1; off < 64; off <<= 1) {
    int v = __shfl_up(incl, off, 64);
    if (lane >= off) incl += v;
  }
  int excl = incl - c;
  int wtot = __shfl(incl, 63, 64);
  int base = 0;
  if (lane == 0) base = atomicAdd(total, wtot);
  base = __shfl(base, 0, 64);
  if (i < n) cursor[i] = base + excl;
}

__global__ __launch_bounds__(256) void k_fill(const int* __restrict__ rows,
                                              const int* __restrict__ cols,
                                              const float* __restrict__ vals,
                                              int* __restrict__ cursor,
                                              int2* __restrict__ csr, int E) {
  int i = blockIdx.x * 256 + threadIdx.x;
  if (i < E) {
    int p = atomicAdd(&cursor[rows[i]], 1);
    int2 pr;
    pr.x = cols[i];
    pr.y = __float_as_int(vals[i]);
    csr[p] = pr;
  }
}

// ---------------- SpMM (bf16 in / bf16 out): Y[i] = sum_e val*X[col] ----------------
// One wave per row, 4-edge unroll for MLP. After k_fill, cursor[row] == row end;
// start = end - cnt[row].
__global__ __launch_bounds__(256) void k_spmm(const unsigned short* __restrict__ X,
                                              const int* __restrict__ endp,
                                              const int* __restrict__ cnt,
                                              const int2* __restrict__ csr,
                                              unsigned short* __restrict__ Y, int n) {
  int row = blockIdx.x * 4 + (threadIdx.x >> 6);
  int lane = threadIdx.x & 63;
  if (row >= n) return;
  int e = endp[row];
  int s = e - cnt[row];
  f32x4 a0 = {0.f, 0.f, 0.f, 0.f};
  f32x4 a1 = a0, a2 = a0, a3 = a0;
  int p = s;
  for (; p + 3 < e; p += 4) {
    int2 e0 = csr[p], e1 = csr[p + 1], e2 = csr[p + 2], e3 = csr[p + 3];
    ushort4 x0 = ((const ushort4*)(X + (size_t)e0.x * HH))[lane];
    ushort4 x1 = ((const ushort4*)(X + (size_t)e1.x * HH))[lane];
    ushort4 x2 = ((const ushort4*)(X + (size_t)e2.x * HH))[lane];
    ushort4 x3 = ((const ushort4*)(X + (size_t)e3.x * HH))[lane];
    a0 += __int_as_float(e0.y) * bf4_to_f32(x0);
    a1 += __int_as_float(e1.y) * bf4_to_f32(x1);
    a2 += __int_as_float(e2.y) * bf4_to_f32(x2);
    a3 += __int_as_float(e3.y) * bf4_to_f32(x3);
  }
  for (; p < e; ++p) {
    int2 e0 = csr[p];
    ushort4 x0 = ((const ushort4*)(X + (size_t)e0.x * HH))[lane];
    a0 += __int_as_float(e0.y) * bf4_to_f32(x0);
  }
  f32x4 a = (a0 + a1) + (a2 + a3);
  ushort4 o;
  o.x = f2bf(a.x); o.y = f2bf(a.y); o.z = f2bf(a.z); o.w = f2bf(a.w);
  ((ushort4*)(Y + (size_t)row * HH))[lane] = o;
}

// ---------------- BatchNorm ----------------
__global__ __launch_bounds__(256) void k_bnstats(const unsigned short* __restrict__ X,
                                                 float* __restrict__ sums, int n) {
  int c = threadIdx.x;
  float s = 0.f, s2 = 0.f;
  for (int r = blockIdx.x; r < n; r += gridDim.x) {
    float v = bf2f(X[(size_t)r * HH + c]);
    s += v; s2 += v * v;
  }
  atomicAdd(&sums[c], s);
  atomicAdd(&sums[HH + c], s2);
}

// y = bf16(relu(x*scale + shift)); scale/shift computed per-block from raw sums
__global__ __launch_bounds__(256) void k_bnrc(const unsigned short* __restrict__ X,
                                              const float* __restrict__ sums,
                                              const float* __restrict__ g,
                                              const float* __restrict__ be,
                                              unsigned short* __restrict__ out, int n4) {
  __shared__ float sc[HH], sh[HH];
  int t = threadIdx.x;
  {
    float inv = 1.f / (float)NN;
    float mean = sums[t] * inv;
    float var = sums[HH + t] * inv - mean * mean;
    float s = g[t] * rsqrtf(var + 1e-5f);
    sc[t] = s;
    sh[t] = be[t] - mean * s;
  }
  __syncthreads();
  for (int i = blockIdx.x * 256 + t; i < n4; i += gridDim.x * 256) {
    f32x4 x = bf4_to_f32(((const ushort4*)X)[i]);
    int c0 = (i * 4) & (HH - 1);
    ushort4 o;
    o.x = f2bf(fmaxf(x.x * sc[c0 + 0] + sh[c0 + 0], 0.f));
    o.y = f2bf(fmaxf(x.y * sc[c0 + 1] + sh[c0 + 1], 0.f));
    o.z = f2bf(fmaxf(x.z * sc[c0 + 2] + sh[c0 + 2], 0.f));
    o.w = f2bf(fmaxf(x.w * sc[c0 + 3] + sh[c0 + 3], 0.f));
    ((ushort4*)out)[i] = o;
  }
}

// ---------------- GEMM: C(MxNn) = A(MxK,bf16) * Bt(NnxK,bf16)^T + bias ----------------
// 128x128 tile, BK=32, 4 waves (2x2), each wave 4x4 grid of 16x16x32 MFMAs.
// OUTB=1: write bf16; OUTB=0: write fp32. gather: A row remap (head on idx rows).
template <int OUTB>
__global__ __launch_bounds__(256, 2) void k_gemm(const unsigned short* __restrict__ A,
                                                 const unsigned short* __restrict__ Bt,
                                                 const float* __restrict__ bias,
                                                 void* __restrict__ Cv,
                                                 int M, int K, int Nn,
                                                 const int* __restrict__ gather) {
  __shared__ unsigned short lA[128 * 32];  // 8 KB, rows of 64B
  __shared__ unsigned short lB[128 * 32];  // 8 KB
  const int tid = threadIdx.x;
  const int wave = tid >> 6, lane = tid & 63;
  const int m0 = blockIdx.x * 128, n0 = blockIdx.y * 128;
  const int wm = (wave >> 1) * 64, wn = (wave & 1) * 64;
  const int lhi = lane >> 4, llo = lane & 15;

  // staging geometry: per issue a wave covers 16 rows x 32 cols (64B rows, 4 lanes/row)
  const int srow = wave * 16 + (lane >> 2);
  const int scol = (lane & 3) * 8;
  int ar0 = m0 + srow, ar1 = m0 + 64 + srow;
  ar0 = ar0 < M ? ar0 : 0;
  ar1 = ar1 < M ? ar1 : 0;
  if (gather) { ar0 = gather[ar0]; ar1 = gather[ar1]; }
  const unsigned short* pA0 = A + (size_t)ar0 * K + scol;
  const unsigned short* pA1 = A + (size_t)ar1 * K + scol;
  const unsigned short* pB0 = Bt + (size_t)(n0 + srow) * K + scol;
  const unsigned short* pB1 = Bt + (size_t)(n0 + 64 + srow) * K + scol;
  unsigned short* dA0 = lA + (wave * 16) * 32;
  unsigned short* dA1 = lA + (64 + wave * 16) * 32;
  unsigned short* dB0 = lB + (wave * 16) * 32;
  unsigned short* dB1 = lB + (64 + wave * 16) * 32;

  f32x4 zero = {0.f, 0.f, 0.f, 0.f};
  f32x4 acc[4][4];
#pragma unroll
  for (int i = 0; i < 4; ++i)
#pragma unroll
    for (int j = 0; j < 4; ++j) acc[i][j] = zero;

  for (int k0 = 0; k0 < K; k0 += 32) {
    gload_lds16(pA0 + k0, dA0);
    gload_lds16(pA1 + k0, dA1);
    gload_lds16(pB0 + k0, dB0);
    gload_lds16(pB1 + k0, dB1);
    __syncthreads();  // drains vmcnt -> LDS valid
    bf16x8 af[4], bfv[4];
#pragma unroll
    for (int mt = 0; mt < 4; ++mt)
      af[mt] = *(const bf16x8*)(lA + (wm + mt * 16 + llo) * 32 + lhi * 8);
#pragma unroll
    for (int nt = 0; nt < 4; ++nt)
      bfv[nt] = *(const bf16x8*)(lB + (wn + nt * 16 + llo) * 32 + lhi * 8);
#pragma unroll
    for (int mt = 0; mt < 4; ++mt)
#pragma unroll
      for (int nt = 0; nt < 4; ++nt)
        acc[mt][nt] = __builtin_amdgcn_mfma_f32_16x16x32_bf16(af[mt], bfv[nt], acc[mt][nt], 0, 0, 0);
    __syncthreads();  // all reads done before next stage
  }

#pragma unroll
  for (int nt = 0; nt < 4; ++nt) {
    int cn = n0 + wn + nt * 16 + llo;
    float bv = bias ? bias[cn] : 0.f;
#pragma unroll
    for (int mt = 0; mt < 4; ++mt) {
      int cm0 = m0 + wm + mt * 16 + lhi * 4;
#pragma unroll
      for (int r = 0; r < 4; ++r) {
        int cm = cm0 + r;
        if (cm < M) {
          float v = acc[mt][nt][r] + bv;
          if (OUTB)
            ((unsigned short*)Cv)[(size_t)cm * Nn + cn] = f2bf(v);
          else
            ((float*)Cv)[(size_t)cm * Nn + cn] = v;
        }
      }
    }
  }
}

extern "C" void kernel_launch(void* const* d_in, const int* in_sizes, int n_in,
                              void* d_out, int out_size, void* d_ws, size_t ws_size,
                              hipStream_t stream) {
  const float* features = (const float*)d_in[0];
  const float* edge_vals = (const float*)d_in[1];
  const float* W1 = (const float*)d_in[2];
  const float* db1 = (const float*)d_in[3];
  // d_in[4] = b1  — annihilated by training-mode BN (constant per column before mean-subtract)
  const float* g1 = (const float*)d_in[5];
  const float* be1 = (const float*)d_in[6];
  const float* W2 = (const float*)d_in[7];
  // d_in[8] = b2  — annihilated by BN
  const float* g2 = (const float*)d_in[9];
  const float* be2 = (const float*)d_in[10];
  const float* Wf = (const float*)d_in[11];
  const float* bfb = (const float*)d_in[12];
  const int* erows = (const int*)d_in[13];
  const int* ecols = (const int*)d_in[14];
  const int* idx = (const int*)d_in[15];
  const int M3 = in_sizes[15];
  (void)n_in; (void)out_size; (void)ws_size;

  char* ws = (char*)d_ws;
  size_t off = 0;
  auto alloc = [&](size_t bytes) -> void* {
    void* p = (void*)(ws + off);
    off += (bytes + 255) & ~(size_t)255;
    return p;
  };
  unsigned short* Xb = (unsigned short*)alloc((size_t)NN * HH * 2);  // features / hidden (bf16)
  unsigned short* Ab = (unsigned short*)alloc((size_t)NN * HH * 2);  // gemm out (bf16)
  unsigned short* Yb = (unsigned short*)alloc((size_t)NN * HH * 2);  // spmm out (bf16)
  unsigned short* W1t = (unsigned short*)alloc((size_t)FF * HH * 2);
  unsigned short* W2t = (unsigned short*)alloc((size_t)HH * HH * 2);
  unsigned short* Wft = (unsigned short*)alloc((size_t)HH * LL * 2);
  int* cursor = (int*)alloc((size_t)NN * 4);
  int* cnt = (int*)alloc((size_t)NN * 4);
  int2* csr = (int2*)alloc((size_t)EE * 8);
  float* stats = (float*)alloc(4 * HH * 4 + 256);  // sums1|sums2|total
  float* sums1 = stats;
  float* sums2 = stats + 2 * HH;
  int* total = (int*)(stats + 4 * HH);

  hipMemsetAsync(cnt, 0, (size_t)NN * 4, stream);
  hipMemsetAsync(stats, 0, 4 * HH * 4 + 256, stream);

  // all dtype conversions in one launch
  k_casts<<<13140, 256, 0, stream>>>(features, Xb, W1, W1t, W2, W2t, Wf, Wft);

  // CSR build (reused by both SpMMs); row bases via unordered atomic allocation
  k_hist<<<(EE + 255) / 256, 256, 0, stream>>>(erows, cnt, EE);
  k_alloc<<<(NN + 255) / 256, 256, 0, stream>>>(cnt, cursor, total, NN);
  k_fill<<<(EE + 255) / 256, 256, 0, stream>>>(erows, ecols, edge_vals, cursor, csr, EE);
  // after k_fill: cursor[row] == row end

  // layer 1
  k_gemm<1><<<dim3((NN + 127) / 128, HH / 128), 256, 0, stream>>>(Xb, W1t, db1, Ab, NN, FF, HH, nullptr);
  k_spmm<<<(NN + 3) / 4, 256, 0, stream>>>(Ab, cursor, cnt, csr, Yb, NN);
  k_bnstats<<<256, 256, 0, stream>>>(Yb, sums1, NN);
  k_bnrc<<<2048, 256, 0, stream>>>(Yb, sums1, g1, be1, Xb, NN * HH / 4);

  // layer 2
  k_gemm<1><<<dim3((NN + 127) / 128, HH / 128), 256, 0, stream>>>(Xb, W2t, nullptr, Ab, NN, HH, HH, nullptr);
  k_spmm<<<(NN + 3) / 4, 256, 0, stream>>>(Ab, cursor, cnt, csr, Yb, NN);
  k_bnstats<<<256, 256, 0, stream>>>(Yb, sums2, NN);
  k_bnrc<<<2048, 256, 0, stream>>>(Yb, sums2, g2, be2, Xb, NN * HH / 4);

  // head: only idx rows, C = H[idx] @ Wf + bf
  k_gemm<0><<<dim3((M3 + 127) / 128, LL / 128), 256, 0, stream>>>(Xb, Wft, bfb, d_out, M3, HH, LL, idx);
}